// Round 16
// baseline (160.573 us; speedup 1.0000x reference)
//
#include <hip/hip_runtime.h>

// Guided blur (multichannel guided filter), B=8, C=Cp=3, H=W=512, k=5, eps=1e-4.
// SINGLE fused kernel, LDS-free, barrier-free, DPP horizontal taps, pair geometry.
// r20 change (P2 contiguous prefetch -> kill per-row vmcnt(0) drains):
//   - r19 post-mortem: spill killed (VGPR 172, WRITE back to 24.6MB) and pair
//     geometry's VALU win is REAL (busy-time 37.8 -> 27.7 us/SIMD vs r13). But dur
//     82.7us at VALUBusy 33.5%: the in-row SUB1 reloads + OUT guidance loads are
//     consumed ~50-100cy after issue; vmcnt is an IN-ORDER counter, so waiting for
//     them = vmcnt(0) = drains the just-issued next-row prefetch -> full L2
//     round-trip stall TWICE per row. Exactly the r12 lesson, reintroduced when the
//     r1 ring was deleted.
//   - Fix: P2[12] distance-1 prefetch of row yb+rr-8, issued contiguously with P at
//     row top (P2 first, then P -> OUT's wait is vmcnt(12), P untouched). Coincidence
//     does double duty: row yb+rr-8 is BOTH next row's SUB1-drop row (yb+(rr+1)-9)
//     AND this row's OUT guidance row -> replaces all 18 in-row loads with 12
//     prefetched ones. All waits now target loads >= ~1400cy old. Guidance cols via
//     shl2 of P2 (g @ x0 of lane u+2 = output col E; x1 -> col O), r13 ring trick.
//   - waves_per_eu(2,2): pin VGPR cap 256 AND forbid the 1-wave/EU regime.
//   - Model: pair VALU floor = 27.7us/SIMD; at r13-like 60-65% busy -> 42-50us.
//   - PASS/FAIL: dur 40-52us & VALUBusy 58-72% = theory right. WRITE_SIZE >30MB =
//     spill tell. dur>=75 & busy<=40 = drain theory wrong -> revert to r13 family.
//   Geometry (r18/r19): 2 adjacent cols/lane; seg s covers raw cols Ob-4..Ob+27
//   (Ob = XO+24s), lane u holds x0=Ob+2u-4, x1=x0+1; outputs u<=11 at cols Ob+2u,+1.
//   Paired 5-tap: t=shl1(E)+O; m=t+shl1(t); sE=E+m; sO=m+shl2(O)  (4 DPP-adds/pair).
//   Sequential E/O solves reuse one S[21] (peak-pressure control, r19). Stage-2 via
//   5-slot hv reg ring + fresh 5-sum under OUT; 1/25 folded into solve outputs.
//   Compile-shape lessons: r5 runtime ring idx -> LDS promotion; r7 vector arrays ->
//   scratch; r8/r17/r18 allocator spills to defend occupancy (WRITE_SIZE tell);
//   r10 wave_shl1 slow; r14 bpermute chains latency-bound; r15 runtime-branch CFG
//   split; r19 in-row-consumed loads -> vmcnt(0) drain.
// No d_ws usage.

namespace {

constexpr int BN = 8;
constexpr int HH = 512;
constexpr int WW = 512;
constexpr int CSZ = HH * WW;
constexpr float GEPS = 1e-4f;
constexpr int OUTW = 96;            // outputs per wave (4 segments x 24)
constexpr int SR   = 16;            // output rows per strip (reads SR+8 raw rows)

__device__ __forceinline__ int refl(int i, int n) {
    // jnp.pad reflect: -1 -> 1, -2 -> 2, n -> n-2, n+1 -> n-3
    if (i < 0) i = -i;
    if (i >= n) i = 2 * n - 2 - i;
    return i;
}

// DPP row_shl:N within each 16-lane row: lane u receives lane u+N (0 past row end).
template <int N>
__device__ __forceinline__ float shlN(float v) {
    return __builtin_bit_cast(float,
        __builtin_amdgcn_update_dpp(0, __builtin_bit_cast(int, v),
                                    0x100 + N, 0xF, 0xF, true));
}

struct St {
    float P[12];          // prefetched next raw row rr+1 (6ch x 2px)
    float P2[12];         // prefetched row yb+rr-8 (6ch x 2px): SUB1@rr+1 + guidance@rr
    float V1[2][21];      // vertical window sums per px (21 stat channels)
    float r2[5][2][12];   // 5-row ring of horizontally-summed scaled a,b per px
};

struct Ctx {
    const float *g0, *g1, *g2, *p0, *p1, *p2;
    float *o0, *o1, *o2;
    int yb, xr0, xr1, xsE, xsO;
    bool wrE, wrO;
};

// Symmetric 3x3 solve from 21 box sums; outputs a,b PRE-SCALED by 0.04 (stage-2 mean).
__device__ __forceinline__ void solveS(const float (&S)[21], float (&A)[12]) {
    const float nrm = 0.04f;  // 1/25
    float mI0 = S[0] * nrm, mI1 = S[1] * nrm, mI2 = S[2] * nrm;
    float mP0 = S[3] * nrm, mP1 = S[4] * nrm, mP2 = S[5] * nrm;
    float v00 = S[6]  * nrm - mI0 * mI0 + GEPS;
    float v01 = S[7]  * nrm - mI0 * mI1;
    float v02 = S[8]  * nrm - mI0 * mI2;
    float v11 = S[9]  * nrm - mI1 * mI1 + GEPS;
    float v12 = S[10] * nrm - mI1 * mI2;
    float v22 = S[11] * nrm - mI2 * mI2 + GEPS;
    float c00 = S[12] * nrm - mI0 * mP0;
    float c01 = S[13] * nrm - mI0 * mP1;
    float c02 = S[14] * nrm - mI0 * mP2;
    float c10 = S[15] * nrm - mI1 * mP0;
    float c11 = S[16] * nrm - mI1 * mP1;
    float c12 = S[17] * nrm - mI1 * mP2;
    float c20 = S[18] * nrm - mI2 * mP0;
    float c21 = S[19] * nrm - mI2 * mP1;
    float c22 = S[20] * nrm - mI2 * mP2;
    float i00 = v11 * v22 - v12 * v12;
    float i01 = v02 * v12 - v01 * v22;
    float i02 = v01 * v12 - v02 * v11;
    float i11 = v00 * v22 - v02 * v02;
    float i12 = v01 * v02 - v00 * v12;
    float i22 = v00 * v11 - v01 * v01;
    float det = v00 * i00 + v01 * i01 + v02 * i02;
    float rd  = __builtin_amdgcn_rcpf(det);
    float rs  = rd * 0.04f;            // fold stage-2 1/25 into a
    A[0] = (i00 * c00 + i01 * c10 + i02 * c20) * rs;
    A[1] = (i00 * c01 + i01 * c11 + i02 * c21) * rs;
    A[2] = (i00 * c02 + i01 * c12 + i02 * c22) * rs;
    A[3] = (i01 * c00 + i11 * c10 + i12 * c20) * rs;
    A[4] = (i01 * c01 + i11 * c11 + i12 * c21) * rs;
    A[5] = (i01 * c02 + i11 * c12 + i12 * c22) * rs;
    A[6] = (i02 * c00 + i12 * c10 + i22 * c20) * rs;
    A[7] = (i02 * c01 + i12 * c11 + i22 * c21) * rs;
    A[8] = (i02 * c02 + i12 * c12 + i22 * c22) * rs;
    // b' = 0.04*(mP - a.mI) with a' = 0.04a already applied
    A[9]  = mP0 * 0.04f - (A[0] * mI0 + A[3] * mI1 + A[6] * mI2);
    A[10] = mP1 * 0.04f - (A[1] * mI0 + A[4] * mI1 + A[7] * mI2);
    A[11] = mP2 * 0.04f - (A[2] * mI0 + A[5] * mI1 + A[8] * mI2);
}

template <int PX>
__device__ __forceinline__ void addStats(St& st, float c0, float c1, float c2,
                                         float c3, float c4, float c5) {
    st.V1[PX][0] += c0; st.V1[PX][1] += c1; st.V1[PX][2] += c2;
    st.V1[PX][3] += c3; st.V1[PX][4] += c4; st.V1[PX][5] += c5;
    st.V1[PX][6]  += c0 * c0; st.V1[PX][7]  += c0 * c1; st.V1[PX][8]  += c0 * c2;
    st.V1[PX][9]  += c1 * c1; st.V1[PX][10] += c1 * c2; st.V1[PX][11] += c2 * c2;
    st.V1[PX][12] += c0 * c3; st.V1[PX][13] += c0 * c4; st.V1[PX][14] += c0 * c5;
    st.V1[PX][15] += c1 * c3; st.V1[PX][16] += c1 * c4; st.V1[PX][17] += c1 * c5;
    st.V1[PX][18] += c2 * c3; st.V1[PX][19] += c2 * c4; st.V1[PX][20] += c2 * c5;
}

template <int PX>
__device__ __forceinline__ void subStats(St& st, float c0, float c1, float c2,
                                         float c3, float c4, float c5) {
    st.V1[PX][0] -= c0; st.V1[PX][1] -= c1; st.V1[PX][2] -= c2;
    st.V1[PX][3] -= c3; st.V1[PX][4] -= c4; st.V1[PX][5] -= c5;
    st.V1[PX][6]  -= c0 * c0; st.V1[PX][7]  -= c0 * c1; st.V1[PX][8]  -= c0 * c2;
    st.V1[PX][9]  -= c1 * c1; st.V1[PX][10] -= c1 * c2; st.V1[PX][11] -= c2 * c2;
    st.V1[PX][12] -= c0 * c3; st.V1[PX][13] -= c0 * c4; st.V1[PX][14] -= c0 * c5;
    st.V1[PX][15] -= c1 * c3; st.V1[PX][16] -= c1 * c4; st.V1[PX][17] -= c1 * c5;
    st.V1[PX][18] -= c2 * c3; st.V1[PX][19] -= c2 * c4; st.V1[PX][20] -= c2 * c5;
}

// One raw row. rr = 5*t + I. Ring slot = constexpr I. Flags constexpr.
// SUB1: rr>=5 (drop row rr-5, from P2 loaded last row); SOLVE: rr>=4; OUT: rr>=8;
// PF: load raw row rr+1 into P; PF2 (rr>=4): load row yb+rr-8 into P2
// (consumed: guidance at OUT this row, SUB1 next row).
template <int I, bool SUB1, bool SOLVE, bool OUT, bool PF, bool PF2>
__device__ __forceinline__ void row(St& st, const Ctx& cx, int t) {
    const int rr = 5 * t + I;

    // capture prefetched current row BEFORE refilling
    float c00 = st.P[0], c01 = st.P[1], c02 = st.P[2];
    float c03 = st.P[3], c04 = st.P[4], c05 = st.P[5];
    float c10 = st.P[6], c11 = st.P[7], c12 = st.P[8];
    float c13 = st.P[9], c14 = st.P[10], c15 = st.P[11];

    // capture old row (rr-5) from P2 (loaded last row) BEFORE refilling
    float o00, o01, o02, o03, o04, o05, o10, o11, o12, o13, o14, o15;
    if constexpr (SUB1) {
        o00 = st.P2[0]; o01 = st.P2[1];  o02 = st.P2[2];
        o03 = st.P2[3]; o04 = st.P2[4];  o05 = st.P2[5];
        o10 = st.P2[6]; o11 = st.P2[7];  o12 = st.P2[8];
        o13 = st.P2[9]; o14 = st.P2[10]; o15 = st.P2[11];
    }

    if constexpr (PF2) {  // row yb+rr-8: guidance for OUT(rr), SUB1 drop for rr+1.
        const int y2 = refl(cx.yb + rr - 8, HH);
        const int a0 = y2 * WW + cx.xr0, a1 = y2 * WW + cx.xr1;
        st.P2[0] = cx.g0[a0]; st.P2[1]  = cx.g1[a0]; st.P2[2]  = cx.g2[a0];
        st.P2[3] = cx.p0[a0]; st.P2[4]  = cx.p1[a0]; st.P2[5]  = cx.p2[a0];
        st.P2[6] = cx.g0[a1]; st.P2[7]  = cx.g1[a1]; st.P2[8]  = cx.g2[a1];
        st.P2[9] = cx.p0[a1]; st.P2[10] = cx.p1[a1]; st.P2[11] = cx.p2[a1];
    }
    if constexpr (PF) {   // next raw row; first use next iteration (issued AFTER P2
                          // so OUT's wait on P2 leaves these in flight)
        const int yn = refl(cx.yb - 4 + rr + 1, HH);
        const int o0 = yn * WW + cx.xr0, o1 = yn * WW + cx.xr1;
        st.P[0] = cx.g0[o0]; st.P[1]  = cx.g1[o0]; st.P[2]  = cx.g2[o0];
        st.P[3] = cx.p0[o0]; st.P[4]  = cx.p1[o0]; st.P[5]  = cx.p2[o0];
        st.P[6] = cx.g0[o1]; st.P[7]  = cx.g1[o1]; st.P[8]  = cx.g2[o1];
        st.P[9] = cx.p0[o1]; st.P[10] = cx.p1[o1]; st.P[11] = cx.p2[o1];
    }

    if constexpr (SUB1) {
        subStats<0>(st, o00, o01, o02, o03, o04, o05);
        subStats<1>(st, o10, o11, o12, o13, o14, o15);
    }
    addStats<0>(st, c00, c01, c02, c03, c04, c05);
    addStats<1>(st, c10, c11, c12, c13, c14, c15);

    if constexpr (SOLVE) {
        // Sequential E then O solve, reusing ONE S buffer (peak-pressure control).
        float S[21], A0[12], A1[12];
#pragma unroll
        for (int c = 0; c < 21; ++c) {
            float tt = shlN<1>(st.V1[0][c]) + st.V1[1][c];
            float m  = tt + shlN<1>(tt);
            S[c] = st.V1[0][c] + m;                    // SE: window starts at x0
        }
        solveS(S, A0);
#pragma unroll
        for (int c = 0; c < 21; ++c) {
            float tt = shlN<1>(st.V1[0][c]) + st.V1[1][c];
            float m  = tt + shlN<1>(tt);
            S[c] = m + shlN<2>(st.V1[1][c]);           // SO: window starts at x1
        }
        solveS(S, A1);

        // stage 2: paired horizontal 5-tap of scaled a,b -> hv ring slot I
#pragma unroll
        for (int c = 0; c < 12; ++c) {
            float tt = shlN<1>(A0[c]) + A1[c];
            float m  = tt + shlN<1>(tt);
            st.r2[I][0][c] = A0[c] + m;
            st.r2[I][1][c] = m + shlN<2>(A1[c]);
        }

        if constexpr (OUT) {
            // vertical 5-sum over the hv ring (rows rr-4..rr), per px
            constexpr int J1 = (I + 1) % 5, J2 = (I + 2) % 5;
            constexpr int J3 = (I + 3) % 5, J4 = (I + 4) % 5;
            float ME[12], MO[12];
#pragma unroll
            for (int c = 0; c < 12; ++c) {
                ME[c] = ((st.r2[I][0][c] + st.r2[J1][0][c]) +
                         (st.r2[J2][0][c] + st.r2[J3][0][c])) + st.r2[J4][0][c];
                MO[c] = ((st.r2[I][1][c] + st.r2[J1][1][c]) +
                         (st.r2[J2][1][c] + st.r2[J3][1][c])) + st.r2[J4][1][c];
            }
            // guidance from P2 (loaded THIS row ~1400cy ago = row yb+rr-8):
            // g @ x0 of lane u+2 = output col E; @ x1 = col O  -> shl2.
            float gE0 = shlN<2>(st.P2[0]), gE1 = shlN<2>(st.P2[1]), gE2 = shlN<2>(st.P2[2]);
            float gO0 = shlN<2>(st.P2[6]), gO1 = shlN<2>(st.P2[7]), gO2 = shlN<2>(st.P2[8]);
            const int yg = cx.yb + rr - 8;          // in [0,511]
            const int oE = yg * WW + cx.xsE, oO = yg * WW + cx.xsO;
            float e0 = gE0 * ME[0] + gE1 * ME[3] + gE2 * ME[6] + ME[9];
            float e1 = gE0 * ME[1] + gE1 * ME[4] + gE2 * ME[7] + ME[10];
            float e2 = gE0 * ME[2] + gE1 * ME[5] + gE2 * ME[8] + ME[11];
            float f0 = gO0 * MO[0] + gO1 * MO[3] + gO2 * MO[6] + MO[9];
            float f1 = gO0 * MO[1] + gO1 * MO[4] + gO2 * MO[7] + MO[10];
            float f2 = gO0 * MO[2] + gO1 * MO[5] + gO2 * MO[8] + MO[11];
            if (cx.wrE) { cx.o0[oE] = e0; cx.o1[oE] = e1; cx.o2[oE] = e2; }
            if (cx.wrO) { cx.o0[oO] = f0; cx.o1[oO] = f1; cx.o2[oO] = f2; }
        }
    }
}

__global__ __launch_bounds__(64)
__attribute__((amdgpu_waves_per_eu(2, 2)))
void fused_kernel(
        const float* __restrict__ g, const float* __restrict__ p,
        float* __restrict__ out) {
    const int lane = threadIdx.x;       // 64 threads = 1 wave, 4 x 16-lane segments
    const int u    = lane & 15;
    const int seg  = lane >> 4;
    const int XO   = blockIdx.x * OUTW;
    const int bb   = blockIdx.z;

    const int Ob  = XO + 24 * seg;      // segment output base col
    const int x0q = Ob + 2 * u - 4;     // raw col of px0 (pre-reflect)
    const int xoE = Ob + 2 * u;         // output col px0 (valid u < 12)
    const int xoO = xoE + 1;

    Ctx cx;
    cx.g0 = g + (size_t)bb * 3 * CSZ; cx.g1 = cx.g0 + CSZ; cx.g2 = cx.g0 + 2 * CSZ;
    cx.p0 = p + (size_t)bb * 3 * CSZ; cx.p1 = cx.p0 + CSZ; cx.p2 = cx.p0 + 2 * CSZ;
    cx.o0 = out + (size_t)bb * 3 * CSZ; cx.o1 = cx.o0 + CSZ; cx.o2 = cx.o0 + 2 * CSZ;
    cx.yb  = blockIdx.y * SR;
    cx.xr0 = refl(x0q, WW);
    cx.xr1 = refl(x0q + 1, WW);
    cx.xsE = (xoE < WW) ? xoE : (WW - 1);
    cx.xsO = (xoO < WW) ? xoO : (WW - 1);
    cx.wrE = (u < 12) && (xoE < WW);
    cx.wrO = (u < 12) && (xoO < WW);

    St st;
#pragma unroll
    for (int x = 0; x < 2; ++x)
#pragma unroll
        for (int i = 0; i < 21; ++i) st.V1[x][i] = 0.f;
    // r2 slots write-before-read (first OUT at rr=8 reads slots written rr=4..8).
    // P2 write-before-read (first read: SUB1@rr=5 reads P2 written @rr=4).

    // prime the prefetch buffer with raw row 0
    {
        const int y0 = refl(cx.yb - 4, HH);
        const int a0 = y0 * WW + cx.xr0, a1 = y0 * WW + cx.xr1;
        st.P[0] = cx.g0[a0]; st.P[1]  = cx.g1[a0]; st.P[2]  = cx.g2[a0];
        st.P[3] = cx.p0[a0]; st.P[4]  = cx.p1[a0]; st.P[5]  = cx.p2[a0];
        st.P[6] = cx.g0[a1]; st.P[7]  = cx.g1[a1]; st.P[8]  = cx.g2[a1];
        st.P[9] = cx.p0[a1]; st.P[10] = cx.p1[a1]; st.P[11] = cx.p2[a1];
    }

    // 24 raw rows (rr=0..23); outputs at rr=8..23 -> rows yb..yb+15.
    // trip 0: rr 0..4 — stats only; first solve rr=4; PF2 starts rr=4
    row<0, false, false, false, true, false>(st, cx, 0);
    row<1, false, false, false, true, false>(st, cx, 0);
    row<2, false, false, false, true, false>(st, cx, 0);
    row<3, false, false, false, true, false>(st, cx, 0);
    row<4, false, true,  false, true, true >(st, cx, 0);
    // trip 1: rr 5..9 — SUB1 on; OUT from rr=8
    row<0, true, true, false, true, true>(st, cx, 1);
    row<1, true, true, false, true, true>(st, cx, 1);
    row<2, true, true, false, true, true>(st, cx, 1);
    row<3, true, true, true,  true, true>(st, cx, 1);
    row<4, true, true, true,  true, true>(st, cx, 1);
    // steady trips: rr 10..19
#pragma unroll 1
    for (int t = 2; t <= 3; ++t) {
        row<0, true, true, true, true, true>(st, cx, t);
        row<1, true, true, true, true, true>(st, cx, t);
        row<2, true, true, true, true, true>(st, cx, t);
        row<3, true, true, true, true, true>(st, cx, t);
        row<4, true, true, true, true, true>(st, cx, t);
    }
    // tail trip 4: rr 20..23 (rr=22 prefetches row 23; rr=23: no PF, PF2 still
    // needed — OUT(23) reads P2 loaded this row)
    row<0, true, true, true, true,  true>(st, cx, 4);
    row<1, true, true, true, true,  true>(st, cx, 4);
    row<2, true, true, true, true,  true>(st, cx, 4);
    row<3, true, true, true, false, true>(st, cx, 4);
}

}  // namespace

extern "C" void kernel_launch(void* const* d_in, const int* in_sizes, int n_in,
                              void* d_out, int out_size, void* d_ws, size_t ws_size,
                              hipStream_t stream) {
    const float* g  = (const float*)d_in[0];   // guidance [8,3,512,512]
    const float* p  = (const float*)d_in[1];   // input    [8,3,512,512]
    float* out = (float*)d_out;                // [8,3,512,512]

    dim3 grid((WW + OUTW - 1) / OUTW, HH / SR, BN);  // (6, 32, 8) = 1536 blocks
    dim3 block(64);

    hipLaunchKernelGGL(fused_kernel, grid, block, 0, stream, g, p, out);
}

// Round 19
// 136.100 us; speedup vs baseline: 1.1798x; 1.1798x over previous
//
#include <hip/hip_runtime.h>

// Guided blur (multichannel guided filter), B=8, C=Cp=3, H=W=512, k=5, eps=1e-4.
// SINGLE fused kernel, LDS-free, barrier-free, DPP horizontal taps, pair geometry.
// r21 change (r19 + P2 contiguous prefetch; waves_per_eu REVERTED to (1,2)):
//   - r20 post-mortem: I broke single-variable discipline — changed BOTH the
//     attribute (1,2)->(2,2) AND added P2. (2,2) reverted the allocator to a
//     128-VGPR budget (VGPR 172->128) and spilled the enlarged state: WRITE_SIZE
//     84.5MB (+60MB scratch), VALUBusy 16%, 170us. P2 was never tested.
//     Allocator facts on record: launch_bounds(64,2)->128+spill; (1,2)->172 clean;
//     (2,2)->128+60MB spill. ONLY (1,2) behaves.
//   - r19 baseline (measured): 82.7us, VALUBusy 33.5%, VGPR 172, WRITE 24.6MB clean.
//     Pair geometry VALU win REAL (27.7us/SIMD busy vs r13's 37.8). Stall = the
//     18 in-row-consumed loads (12 SUB1 reloads + 6 OUT guidance): vmcnt is
//     IN-ORDER, so waiting on them = vmcnt(0) = drains the just-issued next-row
//     prefetch -> L2 round-trip stall twice per row (the r12 lesson).
//   - r21 fix (SINGLE variable vs r19): P2[12] distance-1 prefetch of row yb+rr-8,
//     issued contiguously BEFORE P at row top. Row yb+rr-8 is BOTH next row's
//     SUB1-drop row (yb+(rr+1)-9) AND this row's OUT guidance row -> replaces all
//     18 in-row loads. All waits now target loads >= ~1400cy old. Guidance cols via
//     shl2 of P2 (g @ x0 of lane u+2 = output col E; x1 -> col O). Loads/row 30->24.
//     State 174->186, within (1,2)'s proven headroom.
//   - PASS/FAIL: VGPR 185-215 & WRITE ~24.6MB & dur 40-55us & busy 55-72% = drain
//     theory right. WRITE >30MB = spill -> shrink P2 to guidance-only. WRITE clean
//     but dur ~80us/busy ~33% = drain theory dead -> SR=8 occupancy probe next.
//   Geometry (r18/r19): 2 adjacent cols/lane; seg s covers raw cols Ob-4..Ob+27
//   (Ob = XO+24s), lane u holds x0=Ob+2u-4, x1=x0+1; outputs u<=11 at cols Ob+2u,+1.
//   Paired 5-tap: t=shl1(E)+O; m=t+shl1(t); sE=E+m; sO=m+shl2(O)  (4 DPP-adds/pair).
//   Sequential E/O solves reuse one S[21] (peak-pressure control, r19). Stage-2 via
//   5-slot hv reg ring + fresh 5-sum under OUT; 1/25 folded into solve outputs.
//   Compile-shape lessons: r5 runtime ring idx -> LDS promotion; r7 vector arrays ->
//   scratch; r8/r17/r18/r20 allocator spills to defend occupancy (WRITE_SIZE tell);
//   r10 wave_shl1 slow; r14 bpermute chains latency-bound; r15 runtime-branch CFG
//   split; r19 in-row-consumed loads -> vmcnt(0) drain.
// No d_ws usage.

namespace {

constexpr int BN = 8;
constexpr int HH = 512;
constexpr int WW = 512;
constexpr int CSZ = HH * WW;
constexpr float GEPS = 1e-4f;
constexpr int OUTW = 96;            // outputs per wave (4 segments x 24)
constexpr int SR   = 16;            // output rows per strip (reads SR+8 raw rows)

__device__ __forceinline__ int refl(int i, int n) {
    // jnp.pad reflect: -1 -> 1, -2 -> 2, n -> n-2, n+1 -> n-3
    if (i < 0) i = -i;
    if (i >= n) i = 2 * n - 2 - i;
    return i;
}

// DPP row_shl:N within each 16-lane row: lane u receives lane u+N (0 past row end).
template <int N>
__device__ __forceinline__ float shlN(float v) {
    return __builtin_bit_cast(float,
        __builtin_amdgcn_update_dpp(0, __builtin_bit_cast(int, v),
                                    0x100 + N, 0xF, 0xF, true));
}

struct St {
    float P[12];          // prefetched next raw row rr+1 (6ch x 2px)
    float P2[12];         // prefetched row yb+rr-8 (6ch x 2px): SUB1@rr+1 + guidance@rr
    float V1[2][21];      // vertical window sums per px (21 stat channels)
    float r2[5][2][12];   // 5-row ring of horizontally-summed scaled a,b per px
};

struct Ctx {
    const float *g0, *g1, *g2, *p0, *p1, *p2;
    float *o0, *o1, *o2;
    int yb, xr0, xr1, xsE, xsO;
    bool wrE, wrO;
};

// Symmetric 3x3 solve from 21 box sums; outputs a,b PRE-SCALED by 0.04 (stage-2 mean).
__device__ __forceinline__ void solveS(const float (&S)[21], float (&A)[12]) {
    const float nrm = 0.04f;  // 1/25
    float mI0 = S[0] * nrm, mI1 = S[1] * nrm, mI2 = S[2] * nrm;
    float mP0 = S[3] * nrm, mP1 = S[4] * nrm, mP2 = S[5] * nrm;
    float v00 = S[6]  * nrm - mI0 * mI0 + GEPS;
    float v01 = S[7]  * nrm - mI0 * mI1;
    float v02 = S[8]  * nrm - mI0 * mI2;
    float v11 = S[9]  * nrm - mI1 * mI1 + GEPS;
    float v12 = S[10] * nrm - mI1 * mI2;
    float v22 = S[11] * nrm - mI2 * mI2 + GEPS;
    float c00 = S[12] * nrm - mI0 * mP0;
    float c01 = S[13] * nrm - mI0 * mP1;
    float c02 = S[14] * nrm - mI0 * mP2;
    float c10 = S[15] * nrm - mI1 * mP0;
    float c11 = S[16] * nrm - mI1 * mP1;
    float c12 = S[17] * nrm - mI1 * mP2;
    float c20 = S[18] * nrm - mI2 * mP0;
    float c21 = S[19] * nrm - mI2 * mP1;
    float c22 = S[20] * nrm - mI2 * mP2;
    float i00 = v11 * v22 - v12 * v12;
    float i01 = v02 * v12 - v01 * v22;
    float i02 = v01 * v12 - v02 * v11;
    float i11 = v00 * v22 - v02 * v02;
    float i12 = v01 * v02 - v00 * v12;
    float i22 = v00 * v11 - v01 * v01;
    float det = v00 * i00 + v01 * i01 + v02 * i02;
    float rd  = __builtin_amdgcn_rcpf(det);
    float rs  = rd * 0.04f;            // fold stage-2 1/25 into a
    A[0] = (i00 * c00 + i01 * c10 + i02 * c20) * rs;
    A[1] = (i00 * c01 + i01 * c11 + i02 * c21) * rs;
    A[2] = (i00 * c02 + i01 * c12 + i02 * c22) * rs;
    A[3] = (i01 * c00 + i11 * c10 + i12 * c20) * rs;
    A[4] = (i01 * c01 + i11 * c11 + i12 * c21) * rs;
    A[5] = (i01 * c02 + i11 * c12 + i12 * c22) * rs;
    A[6] = (i02 * c00 + i12 * c10 + i22 * c20) * rs;
    A[7] = (i02 * c01 + i12 * c11 + i22 * c21) * rs;
    A[8] = (i02 * c02 + i12 * c12 + i22 * c22) * rs;
    // b' = 0.04*(mP - a.mI) with a' = 0.04a already applied
    A[9]  = mP0 * 0.04f - (A[0] * mI0 + A[3] * mI1 + A[6] * mI2);
    A[10] = mP1 * 0.04f - (A[1] * mI0 + A[4] * mI1 + A[7] * mI2);
    A[11] = mP2 * 0.04f - (A[2] * mI0 + A[5] * mI1 + A[8] * mI2);
}

template <int PX>
__device__ __forceinline__ void addStats(St& st, float c0, float c1, float c2,
                                         float c3, float c4, float c5) {
    st.V1[PX][0] += c0; st.V1[PX][1] += c1; st.V1[PX][2] += c2;
    st.V1[PX][3] += c3; st.V1[PX][4] += c4; st.V1[PX][5] += c5;
    st.V1[PX][6]  += c0 * c0; st.V1[PX][7]  += c0 * c1; st.V1[PX][8]  += c0 * c2;
    st.V1[PX][9]  += c1 * c1; st.V1[PX][10] += c1 * c2; st.V1[PX][11] += c2 * c2;
    st.V1[PX][12] += c0 * c3; st.V1[PX][13] += c0 * c4; st.V1[PX][14] += c0 * c5;
    st.V1[PX][15] += c1 * c3; st.V1[PX][16] += c1 * c4; st.V1[PX][17] += c1 * c5;
    st.V1[PX][18] += c2 * c3; st.V1[PX][19] += c2 * c4; st.V1[PX][20] += c2 * c5;
}

template <int PX>
__device__ __forceinline__ void subStats(St& st, float c0, float c1, float c2,
                                         float c3, float c4, float c5) {
    st.V1[PX][0] -= c0; st.V1[PX][1] -= c1; st.V1[PX][2] -= c2;
    st.V1[PX][3] -= c3; st.V1[PX][4] -= c4; st.V1[PX][5] -= c5;
    st.V1[PX][6]  -= c0 * c0; st.V1[PX][7]  -= c0 * c1; st.V1[PX][8]  -= c0 * c2;
    st.V1[PX][9]  -= c1 * c1; st.V1[PX][10] -= c1 * c2; st.V1[PX][11] -= c2 * c2;
    st.V1[PX][12] -= c0 * c3; st.V1[PX][13] -= c0 * c4; st.V1[PX][14] -= c0 * c5;
    st.V1[PX][15] -= c1 * c3; st.V1[PX][16] -= c1 * c4; st.V1[PX][17] -= c1 * c5;
    st.V1[PX][18] -= c2 * c3; st.V1[PX][19] -= c2 * c4; st.V1[PX][20] -= c2 * c5;
}

// One raw row. rr = 5*t + I. Ring slot = constexpr I. Flags constexpr.
// SUB1: rr>=5 (drop row rr-5, from P2 loaded last row); SOLVE: rr>=4; OUT: rr>=8;
// PF: load raw row rr+1 into P; PF2 (rr>=4): load row yb+rr-8 into P2
// (consumed: guidance at OUT this row, SUB1 next row).
template <int I, bool SUB1, bool SOLVE, bool OUT, bool PF, bool PF2>
__device__ __forceinline__ void row(St& st, const Ctx& cx, int t) {
    const int rr = 5 * t + I;

    // capture prefetched current row BEFORE refilling
    float c00 = st.P[0], c01 = st.P[1], c02 = st.P[2];
    float c03 = st.P[3], c04 = st.P[4], c05 = st.P[5];
    float c10 = st.P[6], c11 = st.P[7], c12 = st.P[8];
    float c13 = st.P[9], c14 = st.P[10], c15 = st.P[11];

    // capture old row (rr-5) from P2 (loaded last row) BEFORE refilling
    float o00, o01, o02, o03, o04, o05, o10, o11, o12, o13, o14, o15;
    if constexpr (SUB1) {
        o00 = st.P2[0]; o01 = st.P2[1];  o02 = st.P2[2];
        o03 = st.P2[3]; o04 = st.P2[4];  o05 = st.P2[5];
        o10 = st.P2[6]; o11 = st.P2[7];  o12 = st.P2[8];
        o13 = st.P2[9]; o14 = st.P2[10]; o15 = st.P2[11];
    }

    if constexpr (PF2) {  // row yb+rr-8: guidance for OUT(rr), SUB1 drop for rr+1.
        const int y2 = refl(cx.yb + rr - 8, HH);
        const int a0 = y2 * WW + cx.xr0, a1 = y2 * WW + cx.xr1;
        st.P2[0] = cx.g0[a0]; st.P2[1]  = cx.g1[a0]; st.P2[2]  = cx.g2[a0];
        st.P2[3] = cx.p0[a0]; st.P2[4]  = cx.p1[a0]; st.P2[5]  = cx.p2[a0];
        st.P2[6] = cx.g0[a1]; st.P2[7]  = cx.g1[a1]; st.P2[8]  = cx.g2[a1];
        st.P2[9] = cx.p0[a1]; st.P2[10] = cx.p1[a1]; st.P2[11] = cx.p2[a1];
    }
    if constexpr (PF) {   // next raw row; first use next iteration (issued AFTER P2
                          // so OUT's wait on P2 leaves these in flight)
        const int yn = refl(cx.yb - 4 + rr + 1, HH);
        const int o0 = yn * WW + cx.xr0, o1 = yn * WW + cx.xr1;
        st.P[0] = cx.g0[o0]; st.P[1]  = cx.g1[o0]; st.P[2]  = cx.g2[o0];
        st.P[3] = cx.p0[o0]; st.P[4]  = cx.p1[o0]; st.P[5]  = cx.p2[o0];
        st.P[6] = cx.g0[o1]; st.P[7]  = cx.g1[o1]; st.P[8]  = cx.g2[o1];
        st.P[9] = cx.p0[o1]; st.P[10] = cx.p1[o1]; st.P[11] = cx.p2[o1];
    }

    if constexpr (SUB1) {
        subStats<0>(st, o00, o01, o02, o03, o04, o05);
        subStats<1>(st, o10, o11, o12, o13, o14, o15);
    }
    addStats<0>(st, c00, c01, c02, c03, c04, c05);
    addStats<1>(st, c10, c11, c12, c13, c14, c15);

    if constexpr (SOLVE) {
        // Sequential E then O solve, reusing ONE S buffer (peak-pressure control).
        float S[21], A0[12], A1[12];
#pragma unroll
        for (int c = 0; c < 21; ++c) {
            float tt = shlN<1>(st.V1[0][c]) + st.V1[1][c];
            float m  = tt + shlN<1>(tt);
            S[c] = st.V1[0][c] + m;                    // SE: window starts at x0
        }
        solveS(S, A0);
#pragma unroll
        for (int c = 0; c < 21; ++c) {
            float tt = shlN<1>(st.V1[0][c]) + st.V1[1][c];
            float m  = tt + shlN<1>(tt);
            S[c] = m + shlN<2>(st.V1[1][c]);           // SO: window starts at x1
        }
        solveS(S, A1);

        // stage 2: paired horizontal 5-tap of scaled a,b -> hv ring slot I
#pragma unroll
        for (int c = 0; c < 12; ++c) {
            float tt = shlN<1>(A0[c]) + A1[c];
            float m  = tt + shlN<1>(tt);
            st.r2[I][0][c] = A0[c] + m;
            st.r2[I][1][c] = m + shlN<2>(A1[c]);
        }

        if constexpr (OUT) {
            // vertical 5-sum over the hv ring (rows rr-4..rr), per px
            constexpr int J1 = (I + 1) % 5, J2 = (I + 2) % 5;
            constexpr int J3 = (I + 3) % 5, J4 = (I + 4) % 5;
            float ME[12], MO[12];
#pragma unroll
            for (int c = 0; c < 12; ++c) {
                ME[c] = ((st.r2[I][0][c] + st.r2[J1][0][c]) +
                         (st.r2[J2][0][c] + st.r2[J3][0][c])) + st.r2[J4][0][c];
                MO[c] = ((st.r2[I][1][c] + st.r2[J1][1][c]) +
                         (st.r2[J2][1][c] + st.r2[J3][1][c])) + st.r2[J4][1][c];
            }
            // guidance from P2 (loaded THIS row ~1400cy ago = row yb+rr-8):
            // g @ x0 of lane u+2 = output col E; @ x1 = col O  -> shl2.
            float gE0 = shlN<2>(st.P2[0]), gE1 = shlN<2>(st.P2[1]), gE2 = shlN<2>(st.P2[2]);
            float gO0 = shlN<2>(st.P2[6]), gO1 = shlN<2>(st.P2[7]), gO2 = shlN<2>(st.P2[8]);
            const int yg = cx.yb + rr - 8;          // in [0,511]
            const int oE = yg * WW + cx.xsE, oO = yg * WW + cx.xsO;
            float e0 = gE0 * ME[0] + gE1 * ME[3] + gE2 * ME[6] + ME[9];
            float e1 = gE0 * ME[1] + gE1 * ME[4] + gE2 * ME[7] + ME[10];
            float e2 = gE0 * ME[2] + gE1 * ME[5] + gE2 * ME[8] + ME[11];
            float f0 = gO0 * MO[0] + gO1 * MO[3] + gO2 * MO[6] + MO[9];
            float f1 = gO0 * MO[1] + gO1 * MO[4] + gO2 * MO[7] + MO[10];
            float f2 = gO0 * MO[2] + gO1 * MO[5] + gO2 * MO[8] + MO[11];
            if (cx.wrE) { cx.o0[oE] = e0; cx.o1[oE] = e1; cx.o2[oE] = e2; }
            if (cx.wrO) { cx.o0[oO] = f0; cx.o1[oO] = f1; cx.o2[oO] = f2; }
        }
    }
}

__global__ __launch_bounds__(64)
__attribute__((amdgpu_waves_per_eu(1, 2)))
void fused_kernel(
        const float* __restrict__ g, const float* __restrict__ p,
        float* __restrict__ out) {
    const int lane = threadIdx.x;       // 64 threads = 1 wave, 4 x 16-lane segments
    const int u    = lane & 15;
    const int seg  = lane >> 4;
    const int XO   = blockIdx.x * OUTW;
    const int bb   = blockIdx.z;

    const int Ob  = XO + 24 * seg;      // segment output base col
    const int x0q = Ob + 2 * u - 4;     // raw col of px0 (pre-reflect)
    const int xoE = Ob + 2 * u;         // output col px0 (valid u < 12)
    const int xoO = xoE + 1;

    Ctx cx;
    cx.g0 = g + (size_t)bb * 3 * CSZ; cx.g1 = cx.g0 + CSZ; cx.g2 = cx.g0 + 2 * CSZ;
    cx.p0 = p + (size_t)bb * 3 * CSZ; cx.p1 = cx.p0 + CSZ; cx.p2 = cx.p0 + 2 * CSZ;
    cx.o0 = out + (size_t)bb * 3 * CSZ; cx.o1 = cx.o0 + CSZ; cx.o2 = cx.o0 + 2 * CSZ;
    cx.yb  = blockIdx.y * SR;
    cx.xr0 = refl(x0q, WW);
    cx.xr1 = refl(x0q + 1, WW);
    cx.xsE = (xoE < WW) ? xoE : (WW - 1);
    cx.xsO = (xoO < WW) ? xoO : (WW - 1);
    cx.wrE = (u < 12) && (xoE < WW);
    cx.wrO = (u < 12) && (xoO < WW);

    St st;
#pragma unroll
    for (int x = 0; x < 2; ++x)
#pragma unroll
        for (int i = 0; i < 21; ++i) st.V1[x][i] = 0.f;
    // r2 slots write-before-read (first OUT at rr=8 reads slots written rr=4..8).
    // P2 write-before-read (first read: SUB1@rr=5 reads P2 written @rr=4).

    // prime the prefetch buffer with raw row 0
    {
        const int y0 = refl(cx.yb - 4, HH);
        const int a0 = y0 * WW + cx.xr0, a1 = y0 * WW + cx.xr1;
        st.P[0] = cx.g0[a0]; st.P[1]  = cx.g1[a0]; st.P[2]  = cx.g2[a0];
        st.P[3] = cx.p0[a0]; st.P[4]  = cx.p1[a0]; st.P[5]  = cx.p2[a0];
        st.P[6] = cx.g0[a1]; st.P[7]  = cx.g1[a1]; st.P[8]  = cx.g2[a1];
        st.P[9] = cx.p0[a1]; st.P[10] = cx.p1[a1]; st.P[11] = cx.p2[a1];
    }

    // 24 raw rows (rr=0..23); outputs at rr=8..23 -> rows yb..yb+15.
    // trip 0: rr 0..4 — stats only; first solve rr=4; PF2 starts rr=4
    row<0, false, false, false, true, false>(st, cx, 0);
    row<1, false, false, false, true, false>(st, cx, 0);
    row<2, false, false, false, true, false>(st, cx, 0);
    row<3, false, false, false, true, false>(st, cx, 0);
    row<4, false, true,  false, true, true >(st, cx, 0);
    // trip 1: rr 5..9 — SUB1 on; OUT from rr=8
    row<0, true, true, false, true, true>(st, cx, 1);
    row<1, true, true, false, true, true>(st, cx, 1);
    row<2, true, true, false, true, true>(st, cx, 1);
    row<3, true, true, true,  true, true>(st, cx, 1);
    row<4, true, true, true,  true, true>(st, cx, 1);
    // steady trips: rr 10..19
#pragma unroll 1
    for (int t = 2; t <= 3; ++t) {
        row<0, true, true, true, true, true>(st, cx, t);
        row<1, true, true, true, true, true>(st, cx, t);
        row<2, true, true, true, true, true>(st, cx, t);
        row<3, true, true, true, true, true>(st, cx, t);
        row<4, true, true, true, true, true>(st, cx, t);
    }
    // tail trip 4: rr 20..23 (rr=22 prefetches row 23; rr=23: no PF, PF2 still
    // needed — OUT(23) reads P2 loaded this row)
    row<0, true, true, true, true,  true>(st, cx, 4);
    row<1, true, true, true, true,  true>(st, cx, 4);
    row<2, true, true, true, true,  true>(st, cx, 4);
    row<3, true, true, true, false, true>(st, cx, 4);
}

}  // namespace

extern "C" void kernel_launch(void* const* d_in, const int* in_sizes, int n_in,
                              void* d_out, int out_size, void* d_ws, size_t ws_size,
                              hipStream_t stream) {
    const float* g  = (const float*)d_in[0];   // guidance [8,3,512,512]
    const float* p  = (const float*)d_in[1];   // input    [8,3,512,512]
    float* out = (float*)d_out;                // [8,3,512,512]

    dim3 grid((WW + OUTW - 1) / OUTW, HH / SR, BN);  // (6, 32, 8) = 1536 blocks
    dim3 block(64);

    hipLaunchKernelGGL(fused_kernel, grid, block, 0, stream, g, p, out);
}